// Round 4
// baseline (492.105 us; speedup 1.0000x reference)
//
#include <hip/hip_runtime.h>

// TBStars2 MoE sparse block — fp32 I/O, bf16 MFMA compute
// R12: fused fp32->bf16 weight conversion kept, but B-staging latency hidden:
// B(t+1) fp32 prefetched into registers during compute(t) (even/odd named
// sets, no runtime indexing), ds_write+cvt at tile top. Raw s_barrier with
// hand-counted s_waitcnt vmcnt(4) (A gld16 drained, B(t+1) loads in flight),
// sched_barrier(0) pinning issue order and the wait. 2 blocks/CU
// (__launch_bounds__(512,4), small LDS) for cross-block latency cover.
#define T 4096
#define Hdim 1024
#define Fdim 2048
#define NE 8
#define TOPK 2
#define TK (T*TOPK)

typedef unsigned short ushort_t;
typedef __attribute__((ext_vector_type(8))) short bf16x8;   // 8 x bf16 (4 VGPRs)
typedef __attribute__((ext_vector_type(4))) float floatx4;  // mfma accumulator

__device__ __forceinline__ ushort_t f2bf(float f) {
    unsigned u = __float_as_uint(f);
    u += 0x7fff + ((u >> 16) & 1);   // RNE
    return (ushort_t)(u >> 16);
}
__device__ __forceinline__ uint4 cvt8(const float4 a, const float4 b) {
    uint4 r;
    r.x = (unsigned)f2bf(a.x) | ((unsigned)f2bf(a.y) << 16);
    r.y = (unsigned)f2bf(a.z) | ((unsigned)f2bf(a.w) << 16);
    r.z = (unsigned)f2bf(b.x) | ((unsigned)f2bf(b.y) << 16);
    r.w = (unsigned)f2bf(b.z) | ((unsigned)f2bf(b.w) << 16);
    return r;
}
// async 16B global->LDS (per-lane gather src; LDS dest = wave base + lane*16)
__device__ __forceinline__ void gld16(const ushort_t* g, short* l) {
    __builtin_amdgcn_global_load_lds((const __attribute__((address_space(1))) void*)g,
                                     (__attribute__((address_space(3))) void*)l, 16, 0, 0);
}

// ---------------------------------------------------------------------------
// K1: router. One wave per token, fp32. Also converts its hs row -> hsb (bf16)
// and (block 0) zeroes counts.
__global__ __launch_bounds__(64) void router_kernel(
    const float* __restrict__ hs, const float* __restrict__ gw,
    float* __restrict__ logits_out, ushort_t* __restrict__ hsb,
    int2* __restrict__ choice, float2* __restrict__ cwt, int* __restrict__ counts)
{
    const int t = blockIdx.x;
    const int lane = threadIdx.x;
    if (t == 0 && lane < NE) counts[lane] = 0;

    float hreg[16];
#pragma unroll
    for (int i = 0; i < 16; ++i)
        hreg[i] = hs[(long)t * Hdim + lane + 64 * i];

#pragma unroll
    for (int i = 0; i < 16; ++i)
        hsb[(long)t * Hdim + lane + 64 * i] = f2bf(hreg[i]);

    float acc[NE];
#pragma unroll
    for (int e = 0; e < NE; ++e) {
        float s = 0.f;
#pragma unroll
        for (int i = 0; i < 16; ++i)
            s += hreg[i] * gw[e * Hdim + lane + 64 * i];
#pragma unroll
        for (int off = 32; off > 0; off >>= 1)
            s += __shfl_xor(s, off, 64);
        acc[e] = s;
    }

    if (lane < NE) logits_out[t * NE + lane] = acc[lane];

    if (lane == 0) {
        int i1 = 0;
#pragma unroll
        for (int e = 1; e < NE; ++e) if (acc[e] > acc[i1]) i1 = e;
        int i2 = -1;
#pragma unroll
        for (int e = 0; e < NE; ++e) {
            if (e == i1) continue;
            if (i2 < 0 || acc[e] > acc[i2]) i2 = e;
        }
        float p2 = __expf(acc[i2] - acc[i1]);
        float z  = 1.f + p2;
        choice[t] = make_int2(i1, i2);
        cwt[t]    = make_float2(1.f / z, p2 / z);
    }
}

// K1b: scatter. Block = 256 tokens. LDS histogram -> 8 global atomics/block.
__global__ __launch_bounds__(256) void scatter_kernel(
    const int2* __restrict__ choice, const float2* __restrict__ cwt,
    int* __restrict__ counts, int* __restrict__ tok_slot, float* __restrict__ tok_wt)
{
    __shared__ int lhist[NE];
    __shared__ int lbase[NE];
    __shared__ int lpos[NE];
    const int tid = threadIdx.x;
    if (tid < NE) { lhist[tid] = 0; lpos[tid] = 0; }
    __syncthreads();

    const int t = blockIdx.x * 256 + tid;
    int2   ch = choice[t];
    float2 wv = cwt[t];
    atomicAdd(&lhist[ch.x], 1);
    atomicAdd(&lhist[ch.y], 1);
    __syncthreads();

    if (tid < NE) lbase[tid] = atomicAdd(&counts[tid], lhist[tid]);
    __syncthreads();

    int p1 = atomicAdd(&lpos[ch.x], 1);   // ch.x != ch.y
    int p2 = atomicAdd(&lpos[ch.y], 1);
    int o1 = lbase[ch.x] + p1;
    int o2 = lbase[ch.y] + p2;
    tok_slot[ch.x * T + o1] = t * TOPK + 0;
    tok_wt [ch.x * T + o1] = wv.x;
    tok_slot[ch.y * T + o2] = t * TOPK + 1;
    tok_wt [ch.y * T + o2] = wv.y;
}

// ---------------------------------------------------------------------------
// gemm1 staging/compute macros (even/odd register sets — no runtime indexing)
#define G1_LOADB(br, kof)                                              \
    _Pragma("unroll")                                                  \
    for (int i = 0; i < 2; ++i) {                                      \
        br[2*i]   = *(const float4*)(srcBf[i] + (kof));                \
        br[2*i+1] = *(const float4*)(srcBf[i] + (kof) + 4);            \
    }
#define G1_DSWRITE(br)                                                 \
    _Pragma("unroll")                                                  \
    for (int i = 0; i < 2; ++i)                                        \
        *(uint4*)&Bs[bDst[i]] = cvt8(br[2*i], br[2*i+1]);
#define G1_COMPUTE()                                                   \
    _Pragma("unroll")                                                  \
    for (int kk = 0; kk < 2; ++kk) {                                   \
        const int cs = kk ? cs1 : cs0;                                 \
        bf16x8 a[4], g[2], u[2];                                       \
        _Pragma("unroll")                                              \
        for (int ms = 0; ms < 4; ++ms)                                 \
            a[ms] = *(const bf16x8*)&As[(wm + ms * 16 + fr) * 64 + cs];\
        _Pragma("unroll")                                              \
        for (int ns = 0; ns < 2; ++ns) {                               \
            g[ns] = *(const bf16x8*)&Bs[(wn + ns * 16 + fr) * 64 + cs];\
            u[ns] = *(const bf16x8*)&Bs[(64 + wn + ns * 16 + fr) * 64 + cs];\
        }                                                              \
        _Pragma("unroll")                                              \
        for (int ms = 0; ms < 4; ++ms)                                 \
            _Pragma("unroll")                                          \
            for (int ns = 0; ns < 2; ++ns) {                           \
                accg[ms][ns] = __builtin_amdgcn_mfma_f32_16x16x32_bf16(a[ms], g[ns], accg[ms][ns], 0, 0, 0); \
                accu[ms][ns] = __builtin_amdgcn_mfma_f32_16x16x32_bf16(a[ms], u[ns], accu[ms][ns], 0, 0, 0); \
            }                                                          \
    }

// K2: gather-GEMM1 + SwiGLU, fused w1 fp32->bf16. 256 slots x 64 f per block
// (B rows: 64 gate + 64 up), 512 threads = 8 waves (4m x 2n), BK=64, 16
// K-tiles, 49 KB LDS, 2 blocks/CU. A via gld16; B fp32 prefetched to regs
// one K-tile ahead, cvt+ds_write at tile top (zero exposed load latency).
__global__ __launch_bounds__(512, 4) void gemm1_kernel(
    const ushort_t* __restrict__ hsb, const float* __restrict__ w1,
    const int* __restrict__ counts, const int* __restrict__ tok_slot,
    ushort_t* __restrict__ actb)
{
    const int e = blockIdx.z;
    const int cnt = counts[e];
    const int row0 = blockIdx.y * 256;
    if (row0 >= cnt) return;
    const int f0 = blockIdx.x * 64;

    __shared__ short As[256 * 64];    // 32 KB
    __shared__ short Bs[128 * 64];    // 16 KB: rows 0-63 gate, 64-127 up
    __shared__ int slotLds[256];

    const int tid = threadIdx.x;
    if (tid < 256) {
        int idx = row0 + tid;
        slotLds[tid] = (idx < cnt) ? tok_slot[e * T + idx] : -1;
    }
    __syncthreads();

    // A staging: 4 chunks/thread (2048 chunks, gld16, swizzled LDS layout)
    const ushort_t* srcA[4];
#pragma unroll
    for (int i = 0; i < 4; ++i) {
        int ci = i * 512 + tid;            // 0..2047
        int r  = ci >> 3;                  // LDS row 0..255
        int gc = (ci & 7) ^ (r & 7);       // swizzled global chunk
        int s  = slotLds[r];
        srcA[i] = hsb + (long)(s >= 0 ? (s >> 1) : 0) * Hdim + gc * 8;
    }
    // B staging: 2 chunks/thread (1024 chunks), fp32 source, reg-prefetched
    const float* srcBf[2];
    int bDst[2];
#pragma unroll
    for (int i = 0; i < 2; ++i) {
        int ci = i * 512 + tid;            // 0..1023
        int r  = ci >> 3;                  // B LDS row 0..127
        int gc = (ci & 7) ^ (r & 7);
        long frow = (r < 64) ? (long)(f0 + r) : (long)(Fdim + f0 + (r - 64));
        srcBf[i] = w1 + ((long)e * 2 * Fdim + frow) * Hdim + gc * 8;
        bDst[i]  = ci * 8;
    }

    const int lane = tid & 63;
    const int w = tid >> 6;              // 0..7
    const int wm = (w >> 1) * 64;        // slot-row base: 0/64/128/192
    const int wn = (w & 1) * 32;         // f-col base within 64: 0/32
    const int fr = lane & 15, fg = lane >> 4;
    const int cs0 = (fg ^ (fr & 7)) * 8;          // kk=0 chunk swz (elems)
    const int cs1 = ((4 + fg) ^ (fr & 7)) * 8;    // kk=1

    floatx4 accg[4][2] = {};
    floatx4 accu[4][2] = {};

    float4 brE[4], brO[4];
    G1_LOADB(brE, 0);                     // prologue: B(0) -> even set

    for (int t2 = 0; t2 < 8; ++t2) {
        const int kE = 2 * t2 * 64;       // even tile k-offset
        const int kO = kE + 64;           // odd tile k-offset

        // ---- even tile: consume brE, prefetch brO = B(odd) ------------
        if (t2) __builtin_amdgcn_s_barrier();      // compute(prev) done
        G1_DSWRITE(brE);                           // compiler waits brE loads
#pragma unroll
        for (int i = 0; i < 4; ++i) gld16(srcA[i] + kE, &As[(i * 512 + tid) * 8]);
        __builtin_amdgcn_sched_barrier(0);         // pin: A issued before B
        G1_LOADB(brO, kO);
        asm volatile("s_waitcnt vmcnt(4) lgkmcnt(0)" ::: "memory"); // A done, brO in flight
        __builtin_amdgcn_sched_barrier(0);
        __builtin_amdgcn_s_barrier();
        __builtin_amdgcn_s_setprio(1);
        G1_COMPUTE();
        __builtin_amdgcn_s_setprio(0);

        // ---- odd tile: consume brO, prefetch brE = B(next even) -------
        __builtin_amdgcn_s_barrier();
        G1_DSWRITE(brO);
#pragma unroll
        for (int i = 0; i < 4; ++i) gld16(srcA[i] + kO, &As[(i * 512 + tid) * 8]);
        __builtin_amdgcn_sched_barrier(0);
        if (t2 < 7) {
            G1_LOADB(brE, kO + 64);
            asm volatile("s_waitcnt vmcnt(4) lgkmcnt(0)" ::: "memory");
        } else {
            asm volatile("s_waitcnt vmcnt(0) lgkmcnt(0)" ::: "memory");
        }
        __builtin_amdgcn_sched_barrier(0);
        __builtin_amdgcn_s_barrier();
        __builtin_amdgcn_s_setprio(1);
        G1_COMPUTE();
        __builtin_amdgcn_s_setprio(0);
    }

#pragma unroll
    for (int ms = 0; ms < 4; ++ms)
#pragma unroll
        for (int ns = 0; ns < 2; ++ns)
#pragma unroll
            for (int j = 0; j < 4; ++j) {
                int m = wm + ms * 16 + fg * 4 + j;
                int slot = slotLds[m];
                if (slot >= 0) {
                    int fcol = f0 + wn + ns * 16 + fr;
                    float gv = accg[ms][ns][j];
                    float uv = accu[ms][ns][j];
                    float av = (gv / (1.f + __expf(-gv))) * uv;
                    actb[(long)slot * Fdim + fcol] = f2bf(av);
                }
            }
}

// ---------------------------------------------------------------------------
// gemm2 staging/compute macros
#define G2_LOADB(br, kof)                                              \
    _Pragma("unroll")                                                  \
    for (int i = 0; i < 2; ++i) {                                      \
        br[2*i]   = *(const float4*)(srcBf[i] + (kof));                \
        br[2*i+1] = *(const float4*)(srcBf[i] + (kof) + 4);            \
    }
#define G2_DSWRITE(br)                                                 \
    _Pragma("unroll")                                                  \
    for (int i = 0; i < 2; ++i)                                        \
        *(uint4*)&Bs[bDst[i]] = cvt8(br[2*i], br[2*i+1]);
#define G2_COMPUTE()                                                   \
    _Pragma("unroll")                                                  \
    for (int kk = 0; kk < 2; ++kk) {                                   \
        const int cs = kk ? cs1 : cs0;                                 \
        bf16x8 a[4], b[2];                                             \
        _Pragma("unroll")                                              \
        for (int ms = 0; ms < 4; ++ms)                                 \
            a[ms] = *(const bf16x8*)&As[(wm + ms * 16 + fr) * 64 + cs];\
        _Pragma("unroll")                                              \
        for (int ns = 0; ns < 2; ++ns)                                 \
            b[ns] = *(const bf16x8*)&Bs[(wn + ns * 16 + fr) * 64 + cs];\
        _Pragma("unroll")                                              \
        for (int ms = 0; ms < 4; ++ms)                                 \
            _Pragma("unroll")                                          \
            for (int ns = 0; ns < 2; ++ns)                             \
                acc[ms][ns] = __builtin_amdgcn_mfma_f32_16x16x32_bf16(a[ms], b[ns], acc[ms][ns], 0, 0, 0); \
    }

// K3: gather-GEMM2, fused w2 fp32->bf16. 128 x 128 tile, 512 threads
// (8 waves, 2m x 4n), BK=64, 32 K-tiles, 33 KB LDS, 2 blocks/CU. Same
// reg-prefetch pipeline as gemm1. partial[slot, h] = wt * (act @ w2^T).
__global__ __launch_bounds__(512, 4) void gemm2_kernel(
    const ushort_t* __restrict__ actb, const float* __restrict__ w2,
    const int* __restrict__ counts, const int* __restrict__ tok_slot,
    const float* __restrict__ tok_wt, float* __restrict__ partial)
{
    const int e = blockIdx.z;
    const int cnt = counts[e];
    const int row0 = blockIdx.y * 128;
    if (row0 >= cnt) return;
    const int h0 = blockIdx.x * 128;

    __shared__ short As[128 * 64];    // 16 KB
    __shared__ short Bs[128 * 64];    // 16 KB
    __shared__ int   slotLds[128];
    __shared__ float wtLds[128];

    const int tid = threadIdx.x;
    if (tid < 128) {
        int idx = row0 + tid;
        bool ok = idx < cnt;
        slotLds[tid] = ok ? tok_slot[e * T + idx] : -1;
        wtLds[tid]   = ok ? tok_wt [e * T + idx] : 0.f;
    }
    __syncthreads();

    // A staging: 2 chunks/thread (1024 chunks, gld16)
    const ushort_t* srcA[2];
#pragma unroll
    for (int i = 0; i < 2; ++i) {
        int ci = i * 512 + tid;            // 0..1023
        int r  = ci >> 3;                  // A row 0..127
        int gc = (ci & 7) ^ (r & 7);
        int s  = slotLds[r];
        srcA[i] = actb + (long)(s >= 0 ? s : 0) * Fdim + gc * 8;
    }
    // B staging: 2 chunks/thread (1024 chunks), fp32 source, reg-prefetched
    const float* srcBf[2];
    int bDst[2];
#pragma unroll
    for (int i = 0; i < 2; ++i) {
        int ci = i * 512 + tid;            // 0..1023
        int r  = ci >> 3;                  // B row 0..127
        int gc = (ci & 7) ^ (r & 7);
        srcBf[i] = w2 + ((long)e * Hdim + (h0 + r)) * Fdim + gc * 8;
        bDst[i]  = ci * 8;
    }

    const int lane = tid & 63;
    const int w = tid >> 6;              // 0..7
    const int wm = (w >> 2) * 64;        // slot base: 0/64
    const int wn = (w & 3) * 32;         // h base within 128: 0/32/64/96
    const int fr = lane & 15, fg = lane >> 4;
    const int cs0 = (fg ^ (fr & 7)) * 8;
    const int cs1 = ((4 + fg) ^ (fr & 7)) * 8;

    floatx4 acc[4][2] = {};

    float4 brE[4], brO[4];
    G2_LOADB(brE, 0);                     // prologue: B(0) -> even set

    for (int t2 = 0; t2 < 16; ++t2) {
        const int kE = 2 * t2 * 64;
        const int kO = kE + 64;

        // ---- even tile -------------------------------------------------
        if (t2) __builtin_amdgcn_s_barrier();
        G2_DSWRITE(brE);
#pragma unroll
        for (int i = 0; i < 2; ++i) gld16(srcA[i] + kE, &As[(i * 512 + tid) * 8]);
        __builtin_amdgcn_sched_barrier(0);
        G2_LOADB(brO, kO);
        asm volatile("s_waitcnt vmcnt(4) lgkmcnt(0)" ::: "memory"); // A(2) done, brO(4) in flight
        __builtin_amdgcn_sched_barrier(0);
        __builtin_amdgcn_s_barrier();
        __builtin_amdgcn_s_setprio(1);
        G2_COMPUTE();
        __builtin_amdgcn_s_setprio(0);

        // ---- odd tile --------------------------------------------------
        __builtin_amdgcn_s_barrier();
        G2_DSWRITE(brO);
#pragma unroll
        for (int i = 0; i < 2; ++i) gld16(srcA[i] + kO, &As[(i * 512 + tid) * 8]);
        __builtin_amdgcn_sched_barrier(0);
        if (t2 < 15) {
            G2_LOADB(brE, kO + 64);
            asm volatile("s_waitcnt vmcnt(4) lgkmcnt(0)" ::: "memory");
        } else {
            asm volatile("s_waitcnt vmcnt(0) lgkmcnt(0)" ::: "memory");
        }
        __builtin_amdgcn_sched_barrier(0);
        __builtin_amdgcn_s_barrier();
        __builtin_amdgcn_s_setprio(1);
        G2_COMPUTE();
        __builtin_amdgcn_s_setprio(0);
    }

#pragma unroll
    for (int ms = 0; ms < 4; ++ms)
#pragma unroll
        for (int ns = 0; ns < 2; ++ns)
#pragma unroll
            for (int j = 0; j < 4; ++j) {
                int m = wm + ms * 16 + fg * 4 + j;
                int slot = slotLds[m];
                if (slot >= 0) {
                    int hcol = h0 + wn + ns * 16 + fr;
                    partial[(long)slot * Hdim + hcol] = acc[ms][ns][j] * wtLds[m];
                }
            }
}

// ---------------------------------------------------------------------------
// K4: combine the two (token,k) partials -> fp32 final hidden states
__global__ __launch_bounds__(256) void combine_kernel(
    const float* __restrict__ partial, float* __restrict__ out)
{
    long i = (long)blockIdx.x * 256 + threadIdx.x;   // over T*H/4 float4 groups
    int t  = (int)(i / (Hdim / 4));
    int h4 = (int)(i % (Hdim / 4));
    const float4 p0 = *(const float4*)&partial[(long)(2 * t    ) * Hdim + h4 * 4];
    const float4 p1 = *(const float4*)&partial[(long)(2 * t + 1) * Hdim + h4 * 4];
    float4 s;
    s.x = p0.x + p1.x; s.y = p0.y + p1.y; s.z = p0.z + p1.z; s.w = p0.w + p1.w;
    *(float4*)&out[(long)t * Hdim + h4 * 4] = s;
}

// ---------------------------------------------------------------------------
extern "C" void kernel_launch(void* const* d_in, const int* in_sizes, int n_in,
                              void* d_out, int out_size, void* d_ws, size_t ws_size,
                              hipStream_t stream)
{
    const float* hs = (const float*)d_in[0];   // [T, H] fp32
    const float* gw = (const float*)d_in[1];   // [E, H] fp32
    const float* w1 = (const float*)d_in[2];   // [E, 2F, H] fp32
    const float* w2 = (const float*)d_in[3];   // [E, H, F] fp32

    float* out        = (float*)d_out;          // [T*H] final hidden (fp32)
    float* logits_out = out + (long)T * Hdim;   // [T*E] router logits (fp32)

    // workspace (~72.3 MB): choice/cwt alias actb's head (dead before gemm1).
    char* ws = (char*)d_ws;
    size_t off = 0;
    int* counts = (int*)(ws + off);          off += 256;
    int* tok_slot = (int*)(ws + off);        off += (size_t)NE * T * sizeof(int);
    float* tok_wt = (float*)(ws + off);      off += (size_t)NE * T * sizeof(float);
    off = (off + 255) & ~(size_t)255;
    ushort_t* hsb = (ushort_t*)(ws + off);   off += (size_t)T * Hdim * sizeof(ushort_t);   // 8 MB
    off = (off + 255) & ~(size_t)255;
    ushort_t* actb = (ushort_t*)(ws + off);  off += (size_t)TK * Fdim * sizeof(ushort_t);  // 32 MB
    off = (off + 255) & ~(size_t)255;
    float* partial = (float*)(ws + off);     off += (size_t)TK * Hdim * sizeof(float);     // 32 MB
    int2*   choice = (int2*)actb;                       // 32 KB  (dead before gemm1)
    float2* cwt    = (float2*)((char*)actb + (size_t)T * sizeof(int2));   // 32 KB

    router_kernel<<<T, 64, 0, stream>>>(hs, gw, logits_out, hsb, choice, cwt, counts);
    scatter_kernel<<<T / 256, 256, 0, stream>>>(choice, cwt, counts, tok_slot, tok_wt);
    gemm1_kernel<<<dim3(Fdim / 64, T / 256, NE), 512, 0, stream>>>(hsb, w1, counts, tok_slot, actb);
    gemm2_kernel<<<dim3(Hdim / 128, T / 128, NE), 512, 0, stream>>>(actb, w2, counts, tok_slot, tok_wt, partial);
    combine_kernel<<<(int)((long)T * Hdim / 4 / 256), 256, 0, stream>>>(partial, out);
}

// Round 5
// 433.900 us; speedup vs baseline: 1.1341x; 1.1341x over previous
//
#include <hip/hip_runtime.h>

// TBStars2 MoE sparse block — fp32 I/O, bf16 MFMA compute
// R13: revert GEMM cores to best-measured forms (gemm1 = R9 4-phase 256x128,
// gemm2 = R8 128x128, pre-converted bf16 weights via cvt kernels), and delete
// the combine kernel + 32MB partial round-trip: gemm2 atomicAdds wt*y directly
// into out (fp32, device-scope; order-commutative => bit-identical), router
// zeroes each token's out row. R12's reg-prefetch (spilled: VGPR 64 cap,
// WRITE_SIZE 147MB scratch) abandoned.
#define T 4096
#define Hdim 1024
#define Fdim 2048
#define NE 8
#define TOPK 2
#define TK (T*TOPK)

typedef unsigned short ushort_t;
typedef __attribute__((ext_vector_type(8))) short bf16x8;   // 8 x bf16 (4 VGPRs)
typedef __attribute__((ext_vector_type(4))) float floatx4;  // mfma accumulator

__device__ __forceinline__ ushort_t f2bf(float f) {
    unsigned u = __float_as_uint(f);
    u += 0x7fff + ((u >> 16) & 1);   // RNE
    return (ushort_t)(u >> 16);
}
__device__ __forceinline__ uint4 cvt8(const float4 a, const float4 b) {
    uint4 r;
    r.x = (unsigned)f2bf(a.x) | ((unsigned)f2bf(a.y) << 16);
    r.y = (unsigned)f2bf(a.z) | ((unsigned)f2bf(a.w) << 16);
    r.z = (unsigned)f2bf(b.x) | ((unsigned)f2bf(b.y) << 16);
    r.w = (unsigned)f2bf(b.z) | ((unsigned)f2bf(b.w) << 16);
    return r;
}
// async 16B global->LDS (per-lane gather src; LDS dest = wave base + lane*16)
__device__ __forceinline__ void gld16(const ushort_t* g, short* l) {
    __builtin_amdgcn_global_load_lds((const __attribute__((address_space(1))) void*)g,
                                     (__attribute__((address_space(3))) void*)l, 16, 0, 0);
}

// ---------------------------------------------------------------------------
// K0: fp32 -> bf16 convert, exact grid, 8 elems/thread
__global__ __launch_bounds__(256) void cvt_kernel(const float* __restrict__ src,
                                                  ushort_t* __restrict__ dst)
{
    long i = (long)blockIdx.x * 256 + threadIdx.x;
    float4 a = *(const float4*)(src + i * 8);
    float4 b = *(const float4*)(src + i * 8 + 4);
    *(uint4*)(dst + i * 8) = cvt8(a, b);
}

// ---------------------------------------------------------------------------
// K1: router. One wave per token, fp32. Also converts its hs row -> hsb (bf16),
// zeroes its out row (gemm2 accumulates into it atomically), and (block 0)
// zeroes counts.
__global__ __launch_bounds__(64) void router_kernel(
    const float* __restrict__ hs, const float* __restrict__ gw,
    float* __restrict__ logits_out, float* __restrict__ out,
    ushort_t* __restrict__ hsb,
    int2* __restrict__ choice, float2* __restrict__ cwt, int* __restrict__ counts)
{
    const int t = blockIdx.x;
    const int lane = threadIdx.x;
    if (t == 0 && lane < NE) counts[lane] = 0;

    float hreg[16];
#pragma unroll
    for (int i = 0; i < 16; ++i)
        hreg[i] = hs[(long)t * Hdim + lane + 64 * i];

#pragma unroll
    for (int i = 0; i < 16; ++i)
        hsb[(long)t * Hdim + lane + 64 * i] = f2bf(hreg[i]);

    // zero this token's output row (accumulated by gemm2 atomics)
    const float4 z4 = make_float4(0.f, 0.f, 0.f, 0.f);
#pragma unroll
    for (int i = 0; i < 4; ++i)
        *(float4*)&out[(long)t * Hdim + lane * 4 + 256 * i] = z4;

    float acc[NE];
#pragma unroll
    for (int e = 0; e < NE; ++e) {
        float s = 0.f;
#pragma unroll
        for (int i = 0; i < 16; ++i)
            s += hreg[i] * gw[e * Hdim + lane + 64 * i];
#pragma unroll
        for (int off = 32; off > 0; off >>= 1)
            s += __shfl_xor(s, off, 64);
        acc[e] = s;
    }

    if (lane < NE) logits_out[t * NE + lane] = acc[lane];

    if (lane == 0) {
        int i1 = 0;
#pragma unroll
        for (int e = 1; e < NE; ++e) if (acc[e] > acc[i1]) i1 = e;
        int i2 = -1;
#pragma unroll
        for (int e = 0; e < NE; ++e) {
            if (e == i1) continue;
            if (i2 < 0 || acc[e] > acc[i2]) i2 = e;
        }
        float p2 = __expf(acc[i2] - acc[i1]);
        float z  = 1.f + p2;
        choice[t] = make_int2(i1, i2);
        cwt[t]    = make_float2(1.f / z, p2 / z);
    }
}

// K1b: scatter. Block = 256 tokens. LDS histogram -> 8 global atomics/block.
__global__ __launch_bounds__(256) void scatter_kernel(
    const int2* __restrict__ choice, const float2* __restrict__ cwt,
    int* __restrict__ counts, int* __restrict__ tok_slot, float* __restrict__ tok_wt)
{
    __shared__ int lhist[NE];
    __shared__ int lbase[NE];
    __shared__ int lpos[NE];
    const int tid = threadIdx.x;
    if (tid < NE) { lhist[tid] = 0; lpos[tid] = 0; }
    __syncthreads();

    const int t = blockIdx.x * 256 + tid;
    int2   ch = choice[t];
    float2 wv = cwt[t];
    atomicAdd(&lhist[ch.x], 1);
    atomicAdd(&lhist[ch.y], 1);
    __syncthreads();

    if (tid < NE) lbase[tid] = atomicAdd(&counts[tid], lhist[tid]);
    __syncthreads();

    int p1 = atomicAdd(&lpos[ch.x], 1);   // ch.x != ch.y
    int p2 = atomicAdd(&lpos[ch.y], 1);
    int o1 = lbase[ch.x] + p1;
    int o2 = lbase[ch.y] + p2;
    tok_slot[ch.x * T + o1] = t * TOPK + 0;
    tok_wt [ch.x * T + o1] = wv.x;
    tok_slot[ch.y * T + o2] = t * TOPK + 1;
    tok_wt [ch.y * T + o2] = wv.y;
}

// ---------------------------------------------------------------------------
// K2: gather-GEMM1 + SwiGLU. 256 slots x 128 f (B rows: 128 gate + 128 up),
// 512 threads = 8 waves (4m x 2fn), BK=64, 16 K-tiles, double-buffered LDS
// (128 KB), 4 phases/K-tile (R9 form — best measured 105 us).
__global__ __launch_bounds__(512) void gemm1_kernel(
    const ushort_t* __restrict__ hsb, const ushort_t* __restrict__ w1b,
    const int* __restrict__ counts, const int* __restrict__ tok_slot,
    ushort_t* __restrict__ actb)
{
    const int e = blockIdx.z;
    const int cnt = counts[e];
    const int row0 = blockIdx.y * 256;
    if (row0 >= cnt) return;
    const int f0 = blockIdx.x * 128;

    __shared__ short As[2][256 * 64];    // 2 x 32 KB
    __shared__ short Bs[2][256 * 64];    // 2 x 32 KB: rows 0-127 gate, 128-255 up
    __shared__ int slotLds[256];

    const int tid = threadIdx.x;
    if (tid < 256) {
        int idx = row0 + tid;
        slotLds[tid] = (idx < cnt) ? tok_slot[e * T + idx] : -1;
    }
    __syncthreads();

    // staging pointers: 4 A-chunks + 4 B-chunks per thread (2048 chunks each)
    const ushort_t* srcA[4];
    const ushort_t* srcB[4];
#pragma unroll
    for (int i = 0; i < 4; ++i) {
        int ci = i * 512 + tid;            // 0..2047
        int r  = ci >> 3;                  // LDS row 0..255
        int gc = (ci & 7) ^ (r & 7);       // swizzled global chunk
        int s  = slotLds[r];
        srcA[i] = hsb + (long)(s >= 0 ? (s >> 1) : 0) * Hdim + gc * 8;
        long frow = (r < 128) ? (long)(f0 + r) : (long)(Fdim + f0 + (r - 128));
        srcB[i] = w1b + ((long)e * 2 * Fdim + frow) * Hdim + gc * 8;
    }

    const int lane = tid & 63;
    const int w = tid >> 6;              // 0..7
    const int wm = (w >> 1) * 64;        // slot-row base: 0/64/128/192
    const int fn = (w & 1) * 64;         // f-col base within 128: 0/64
    const int fr = lane & 15, fg = lane >> 4;
    const int cs0 = (fg ^ (fr & 7)) * 8;          // kk=0 chunk byte-swz (elems)
    const int cs1 = ((4 + fg) ^ (fr & 7)) * 8;    // kk=1

    floatx4 accg[4][4] = {};
    floatx4 accu[4][4] = {};

    // prologue: stage K-tile 0 into buffer 0, full drain
#pragma unroll
    for (int i = 0; i < 4; ++i) {
        gld16(srcA[i], &As[0][(i * 512 + tid) * 8]);
        gld16(srcB[i], &Bs[0][(i * 512 + tid) * 8]);
    }
    __syncthreads();

    const int NT = Hdim / 64;            // 16 K-tiles
    for (int t = 0; t < NT; ++t) {
        short* Ac = As[t & 1];
        short* Bc = Bs[t & 1];
        short* An = As[(t & 1) ^ 1];
        short* Bn = Bs[(t & 1) ^ 1];
        const bool pf = (t + 1 < NT);
        const long k1 = (long)(t + 1) * 64;

        bf16x8 a[4], b[4];

        // ---- phase 0: kk=0, gate -------------------------------------
#pragma unroll
        for (int ms = 0; ms < 4; ++ms)
            a[ms] = *(const bf16x8*)&Ac[(wm + ms * 16 + fr) * 64 + cs0];
#pragma unroll
        for (int ns = 0; ns < 4; ++ns)
            b[ns] = *(const bf16x8*)&Bc[(fn + ns * 16 + fr) * 64 + cs0];
        if (pf) {
            gld16(srcA[0] + k1, &An[(0 * 512 + tid) * 8]);
            gld16(srcB[0] + k1, &Bn[(0 * 512 + tid) * 8]);
        }
        __builtin_amdgcn_s_barrier();
        __builtin_amdgcn_s_setprio(1);
#pragma unroll
        for (int ms = 0; ms < 4; ++ms)
#pragma unroll
            for (int ns = 0; ns < 4; ++ns)
                accg[ms][ns] = __builtin_amdgcn_mfma_f32_16x16x32_bf16(a[ms], b[ns], accg[ms][ns], 0, 0, 0);
        __builtin_amdgcn_s_setprio(0);
        __builtin_amdgcn_s_barrier();

        // ---- phase 1: kk=0, up (reuses a) ----------------------------
#pragma unroll
        for (int ns = 0; ns < 4; ++ns)
            b[ns] = *(const bf16x8*)&Bc[(128 + fn + ns * 16 + fr) * 64 + cs0];
        if (pf) {
            gld16(srcA[1] + k1, &An[(1 * 512 + tid) * 8]);
            gld16(srcB[1] + k1, &Bn[(1 * 512 + tid) * 8]);
        }
        __builtin_amdgcn_s_barrier();
        __builtin_amdgcn_s_setprio(1);
#pragma unroll
        for (int ms = 0; ms < 4; ++ms)
#pragma unroll
            for (int ns = 0; ns < 4; ++ns)
                accu[ms][ns] = __builtin_amdgcn_mfma_f32_16x16x32_bf16(a[ms], b[ns], accu[ms][ns], 0, 0, 0);
        __builtin_amdgcn_s_setprio(0);
        __builtin_amdgcn_s_barrier();

        // ---- phase 2: kk=1, gate -------------------------------------
#pragma unroll
        for (int ms = 0; ms < 4; ++ms)
            a[ms] = *(const bf16x8*)&Ac[(wm + ms * 16 + fr) * 64 + cs1];
#pragma unroll
        for (int ns = 0; ns < 4; ++ns)
            b[ns] = *(const bf16x8*)&Bc[(fn + ns * 16 + fr) * 64 + cs1];
        if (pf) {
            gld16(srcA[2] + k1, &An[(2 * 512 + tid) * 8]);
            gld16(srcB[2] + k1, &Bn[(2 * 512 + tid) * 8]);
        }
        __builtin_amdgcn_s_barrier();
        __builtin_amdgcn_s_setprio(1);
#pragma unroll
        for (int ms = 0; ms < 4; ++ms)
#pragma unroll
            for (int ns = 0; ns < 4; ++ns)
                accg[ms][ns] = __builtin_amdgcn_mfma_f32_16x16x32_bf16(a[ms], b[ns], accg[ms][ns], 0, 0, 0);
        __builtin_amdgcn_s_setprio(0);
        __builtin_amdgcn_s_barrier();

        // ---- phase 3: kk=1, up; K-tile boundary drain ----------------
#pragma unroll
        for (int ns = 0; ns < 4; ++ns)
            b[ns] = *(const bf16x8*)&Bc[(128 + fn + ns * 16 + fr) * 64 + cs1];
        if (pf) {
            gld16(srcA[3] + k1, &An[(3 * 512 + tid) * 8]);
            gld16(srcB[3] + k1, &Bn[(3 * 512 + tid) * 8]);
        }
        __builtin_amdgcn_s_barrier();
        __builtin_amdgcn_s_setprio(1);
#pragma unroll
        for (int ms = 0; ms < 4; ++ms)
#pragma unroll
            for (int ns = 0; ns < 4; ++ns)
                accu[ms][ns] = __builtin_amdgcn_mfma_f32_16x16x32_bf16(a[ms], b[ns], accu[ms][ns], 0, 0, 0);
        __builtin_amdgcn_s_setprio(0);
        __builtin_amdgcn_sched_barrier(0);
        asm volatile("s_waitcnt vmcnt(0)" ::: "memory");
        __builtin_amdgcn_s_barrier();
    }

#pragma unroll
    for (int ms = 0; ms < 4; ++ms)
#pragma unroll
        for (int ns = 0; ns < 4; ++ns)
#pragma unroll
            for (int j = 0; j < 4; ++j) {
                int m = wm + ms * 16 + fg * 4 + j;
                int slot = slotLds[m];
                if (slot >= 0) {
                    int fcol = f0 + fn + ns * 16 + fr;
                    float gv = accg[ms][ns][j];
                    float uv = accu[ms][ns][j];
                    float av = (gv / (1.f + __expf(-gv))) * uv;
                    actb[(long)slot * Fdim + fcol] = f2bf(av);
                }
            }
}

// ---------------------------------------------------------------------------
// K3: gather-GEMM2, 128x128 tile, 512 threads (8 waves, 2x4), BK=64, 32 steps
// (R8 form). Epilogue: atomicAdd wt*y directly into out[token, h] (replaces
// partial + combine; fp32 add is order-commutative -> bit-identical).
__global__ __launch_bounds__(512) void gemm2_kernel(
    const ushort_t* __restrict__ actb, const ushort_t* __restrict__ w2b,
    const int* __restrict__ counts, const int* __restrict__ tok_slot,
    const float* __restrict__ tok_wt, float* __restrict__ out)
{
    const int e = blockIdx.z;
    const int cnt = counts[e];
    const int row0 = blockIdx.y * 128;
    if (row0 >= cnt) return;
    const int h0 = blockIdx.x * 128;

    __shared__ short As[128 * 64];
    __shared__ short Bs[128 * 64];
    __shared__ int   slotLds[128];
    __shared__ float wtLds[128];

    const int tid = threadIdx.x;
    if (tid < 128) {
        int idx = row0 + tid;
        bool ok = idx < cnt;
        slotLds[tid] = ok ? tok_slot[e * T + idx] : -1;
        wtLds[tid]   = ok ? tok_wt [e * T + idx] : 0.f;
    }
    __syncthreads();

    const ushort_t* srcA[2];
    const ushort_t* srcB[2];
#pragma unroll
    for (int i = 0; i < 2; ++i) {
        int ci = i * 512 + tid;            // 0..1023
        int r  = ci >> 3;
        int gc = (ci & 7) ^ (r & 7);
        int s  = slotLds[r];
        srcA[i] = actb + (long)(s >= 0 ? s : 0) * Fdim + gc * 8;
        srcB[i] = w2b + ((long)e * Hdim + (h0 + r)) * Fdim + gc * 8;
    }

    const int lane = tid & 63;
    const int w = tid >> 6;              // 0..7
    const int wm = (w >> 2) * 64;
    const int wn = (w & 3) * 32;
    const int fr = lane & 15, fg = lane >> 4;
    const int cs0 = (fg ^ (fr & 7)) * 8;
    const int cs1 = ((4 + fg) ^ (fr & 7)) * 8;

    floatx4 acc[4][2] = {};

    for (int k0 = 0; k0 < Fdim; k0 += 64) {
        __syncthreads();
        gld16(srcA[0] + k0, &As[tid * 8]);
        gld16(srcA[1] + k0, &As[(512 + tid) * 8]);
        gld16(srcB[0] + k0, &Bs[tid * 8]);
        gld16(srcB[1] + k0, &Bs[(512 + tid) * 8]);
        __syncthreads();

#pragma unroll
        for (int kk = 0; kk < 2; ++kk) {
            const int cs = kk ? cs1 : cs0;
            bf16x8 a[4], b[2];
#pragma unroll
            for (int ms = 0; ms < 4; ++ms)
                a[ms] = *(bf16x8*)&As[(wm + ms * 16 + fr) * 64 + cs];
#pragma unroll
            for (int ns = 0; ns < 2; ++ns)
                b[ns] = *(bf16x8*)&Bs[(wn + ns * 16 + fr) * 64 + cs];
#pragma unroll
            for (int ms = 0; ms < 4; ++ms)
#pragma unroll
                for (int ns = 0; ns < 2; ++ns)
                    acc[ms][ns] = __builtin_amdgcn_mfma_f32_16x16x32_bf16(a[ms], b[ns], acc[ms][ns], 0, 0, 0);
        }
    }

#pragma unroll
    for (int ms = 0; ms < 4; ++ms)
#pragma unroll
        for (int ns = 0; ns < 2; ++ns)
#pragma unroll
            for (int j = 0; j < 4; ++j) {
                int m = wm + ms * 16 + fg * 4 + j;
                int slot = slotLds[m];
                if (slot >= 0) {
                    int hcol = h0 + wn + ns * 16 + fr;
                    atomicAdd(&out[(long)(slot >> 1) * Hdim + hcol],
                              acc[ms][ns][j] * wtLds[m]);
                }
            }
}

// ---------------------------------------------------------------------------
extern "C" void kernel_launch(void* const* d_in, const int* in_sizes, int n_in,
                              void* d_out, int out_size, void* d_ws, size_t ws_size,
                              hipStream_t stream)
{
    const float* hs = (const float*)d_in[0];   // [T, H] fp32
    const float* gw = (const float*)d_in[1];   // [E, H] fp32
    const float* w1 = (const float*)d_in[2];   // [E, 2F, H] fp32
    const float* w2 = (const float*)d_in[3];   // [E, H, F] fp32

    float* out        = (float*)d_out;          // [T*H] final hidden (fp32)
    float* logits_out = out + (long)T * Hdim;   // [T*E] router logits (fp32)

    // workspace (~72.3 MB): w1region recycled after gemm1 (lower 32 MB = w2b).
    // choice/cwt alias actb's head (dead before gemm1). No partial buffer.
    char* ws = (char*)d_ws;
    size_t off = 0;
    int* counts = (int*)(ws + off);          off += 256;
    int* tok_slot = (int*)(ws + off);        off += (size_t)NE * T * sizeof(int);
    float* tok_wt = (float*)(ws + off);      off += (size_t)NE * T * sizeof(float);
    off = (off + 255) & ~(size_t)255;
    ushort_t* hsb = (ushort_t*)(ws + off);   off += (size_t)T * Hdim * sizeof(ushort_t);   // 8 MB
    off = (off + 255) & ~(size_t)255;
    char* w1region = ws + off;               off += (size_t)NE * 2 * Fdim * Hdim * sizeof(ushort_t); // 64 MB
    ushort_t* w1b = (ushort_t*)w1region;
    ushort_t* w2b = (ushort_t*)w1region;                                     // 32 MB (lower half)
    off = (off + 255) & ~(size_t)255;
    ushort_t* actb = (ushort_t*)(ws + off);  off += (size_t)TK * Fdim * sizeof(ushort_t);  // 32 MB
    int2*   choice = (int2*)actb;                       // 32 KB  (dead before gemm1)
    float2* cwt    = (float2*)((char*)actb + (size_t)T * sizeof(int2));   // 32 KB

    const long n8_w1 = (long)NE * 2 * Fdim * Hdim / 8;        //  4194304
    const long n8_w2 = (long)NE * Hdim * Fdim / 8;            //  2097152

    cvt_kernel<<<(int)(n8_w1 / 256), 256, 0, stream>>>(w1, w1b);
    router_kernel<<<T, 64, 0, stream>>>(hs, gw, logits_out, out, hsb, choice, cwt, counts);
    scatter_kernel<<<T / 256, 256, 0, stream>>>(choice, cwt, counts, tok_slot, tok_wt);
    gemm1_kernel<<<dim3(Fdim / 128, T / 256, NE), 512, 0, stream>>>(hsb, w1b, counts, tok_slot, actb);
    cvt_kernel<<<(int)(n8_w2 / 256), 256, 0, stream>>>(w2, w2b);   // into recycled w1b (lower half)
    gemm2_kernel<<<dim3(Hdim / 128, T / 128, NE), 512, 0, stream>>>(actb, w2b, counts, tok_slot, tok_wt, out);
}